// Round 5
// baseline (147.442 us; speedup 1.0000x reference)
//
#include <hip/hip_runtime.h>
#include <stdint.h>

typedef __attribute__((ext_vector_type(8))) short short8v;
typedef __attribute__((ext_vector_type(4))) float float4v;
typedef __attribute__((ext_vector_type(4))) unsigned short ushort4v;
typedef __attribute__((ext_vector_type(2))) unsigned int uint2v;

#define B_SZ 2
#define T_SEQ 2048
#define C_EMB 1024
#define NH 16
#define DH 64
#define M_ROWS (B_SZ * T_SEQ)
#define CEXP 0.18033688f        /* (1/sqrt(64)) * log2(e) */
#define DEFER_THR 44.3614f      /* 8 / CEXP -> P bounded by 2^8 */

__device__ __forceinline__ unsigned short f2bf(float f) {
    unsigned int u = __float_as_uint(f);
    u += 0x7FFFu + ((u >> 16) & 1u);   // RTNE
    return (unsigned short)(u >> 16);
}

__device__ __forceinline__ unsigned int cvtpk_bf16(float lo, float hi) {
    unsigned int r;
    asm("v_cvt_pk_bf16_f32 %0, %1, %2" : "=v"(r) : "v"(lo), "v"(hi));
    return r;
}

__device__ __forceinline__ void gload_lds16(const void* g, void* s) {
    __builtin_amdgcn_global_load_lds(
        (const __attribute__((address_space(1))) void*)g,
        (__attribute__((address_space(3))) void*)s, 16, 0, 0);
}

__device__ __forceinline__ void memfence_sched() { asm volatile("" ::: "memory"); }

__device__ __forceinline__ void block_barrier() {
    memfence_sched();
    __builtin_amdgcn_s_barrier();
    memfence_sched();
}

// ---------------- x f32 -> bf16 ----------------
__global__ __launch_bounds__(256) void k_cvt_x(const float* __restrict__ in,
                                               unsigned short* __restrict__ out, int n4) {
    int i = blockIdx.x * 256 + threadIdx.x;
    if (i >= n4) return;
    float4v v = ((const float4v*)in)[i];
    ushort4v o;
    o.x = f2bf(v.x); o.y = f2bf(v.y); o.z = f2bf(v.z); o.w = f2bf(v.w);
    ((ushort4v*)out)[i] = o;
}

// ------------- W f32 [R][C] -> bf16 [C][R] -------------
__global__ __launch_bounds__(256) void k_transpose_cvt(const float* __restrict__ in,
                                                       unsigned short* __restrict__ out,
                                                       int R, int C) {
    __shared__ float tile[64][65];
    int c0 = blockIdx.x * 64;
    int r0 = blockIdx.y * 64;
#pragma unroll
    for (int i = 0; i < 16; ++i) {
        int e = i * 256 + threadIdx.x;
        int r = e >> 6, c = e & 63;
        tile[r][c] = in[(size_t)(r0 + r) * C + c0 + c];
    }
    __syncthreads();
#pragma unroll
    for (int i = 0; i < 16; ++i) {
        int e = i * 256 + threadIdx.x;
        int r = e >> 6, c = e & 63;
        out[(size_t)(c0 + r) * R + r0 + c] = f2bf(tile[c][r]);
    }
}

// ------------- GEMM: C = A * Bt^T, tri-buffered single-barrier pipeline -------------
__global__ __launch_bounds__(256) void k_gemm_bt(const unsigned short* __restrict__ A,
                                                 const unsigned short* __restrict__ Bt,
                                                 void* __restrict__ Cout,
                                                 int M, int N, int K, int out_f32) {
    __shared__ __align__(16) unsigned short As[3][128 * 32];
    __shared__ __align__(16) unsigned short Bs[3][128 * 32];

    const int tid = threadIdx.x;
    const int lane = tid & 63;
    const int w = tid >> 6;
    const int lr = lane & 15;
    const int lg = lane >> 4;
    const int wr = (w >> 1) * 64;
    const int wc = (w & 1) * 64;

    // XCD-chunked bijective swizzle (nwg % 8 == 0 guaranteed by launch shapes)
    const int gx = gridDim.x;
    const int nwg = gx * gridDim.y;
    const int lin = blockIdx.y * gx + blockIdx.x;
    const int q8 = nwg >> 3;
    const int wg = (lin & 7) * q8 + (lin >> 3);
    const int mb = wg / gx;
    const int nb = wg - mb * gx;
    const int m0 = mb * 128;
    const int n0 = nb * 128;

    const unsigned short* aptr = A + (size_t)(m0 + (tid >> 2)) * K + (tid & 3) * 8;
    const unsigned short* bptr = Bt + (size_t)(n0 + (tid >> 2)) * K + (tid & 3) * 8;

    float4v acc[4][4];
#pragma unroll
    for (int i = 0; i < 4; ++i)
#pragma unroll
        for (int j = 0; j < 4; ++j) acc[i][j] = (float4v){0.f, 0.f, 0.f, 0.f};

#define G_STAGE(buf, t)                                                        \
    do {                                                                       \
        const int k0_ = (t) * 32;                                              \
        gload_lds16(aptr + k0_, &As[buf][tid * 8]);                            \
        gload_lds16(aptr + (size_t)64 * K + k0_, &As[buf][2048 + tid * 8]);    \
        gload_lds16(bptr + k0_, &Bs[buf][tid * 8]);                            \
        gload_lds16(bptr + (size_t)64 * K + k0_, &Bs[buf][2048 + tid * 8]);    \
    } while (0)

    const int NT = K >> 5;
    G_STAGE(0, 0);
    G_STAGE(1, 1);

    int cur = 0;
    for (int t = 0; t < NT; ++t) {
        if (t < NT - 1) { asm volatile("s_waitcnt vmcnt(4)" ::: "memory"); }
        else           { asm volatile("s_waitcnt vmcnt(0)" ::: "memory"); }
        block_barrier();
        if (t + 2 < NT) { G_STAGE((cur == 0 ? 2 : cur - 1), t + 2); }

        short8v af[4], bf[4];
#pragma unroll
        for (int i = 0; i < 4; ++i)
            af[i] = *(const short8v*)&As[cur][(wr + i * 16 + lr) * 32 + lg * 8];
#pragma unroll
        for (int i = 0; i < 4; ++i)
            bf[i] = *(const short8v*)&Bs[cur][(wc + i * 16 + lr) * 32 + lg * 8];
        __builtin_amdgcn_s_setprio(1);
#pragma unroll
        for (int mi = 0; mi < 4; ++mi)
#pragma unroll
            for (int ni = 0; ni < 4; ++ni)
                acc[mi][ni] = __builtin_amdgcn_mfma_f32_16x16x32_bf16(af[mi], bf[ni],
                                                                      acc[mi][ni], 0, 0, 0);
        __builtin_amdgcn_s_setprio(0);
        cur = (cur == 2) ? 0 : cur + 1;
    }
#undef G_STAGE

#pragma unroll
    for (int mi = 0; mi < 4; ++mi) {
#pragma unroll
        for (int ni = 0; ni < 4; ++ni) {
            int row = m0 + wr + mi * 16 + lg * 4;
            int col = n0 + wc + ni * 16 + lr;
            if (out_f32) {
                float* Cf = (float*)Cout;
#pragma unroll
                for (int r = 0; r < 4; ++r) Cf[(size_t)(row + r) * N + col] = acc[mi][ni][r];
            } else {
                unsigned short* Cb = (unsigned short*)Cout;
#pragma unroll
                for (int r = 0; r < 4; ++r) Cb[(size_t)(row + r) * N + col] = f2bf(acc[mi][ni][r]);
            }
        }
    }
}

// ------------- V-part of qkv -> v_t[b,h,d,t] (bf16) -------------
__global__ __launch_bounds__(256) void k_transpose_v(const unsigned short* __restrict__ qkv,
                                                     unsigned short* __restrict__ vt) {
    __shared__ unsigned short tile[64][72];
    int t0 = blockIdx.x * 64;
    int bh = blockIdx.y;
    int b = bh >> 4, h = bh & 15;
#pragma unroll
    for (int i = 0; i < 2; ++i) {
        int e = i * 256 + threadIdx.x;
        int tt = e >> 3, db = (e & 7) * 8;
        short8v v = *(const short8v*)&qkv[(size_t)(b * T_SEQ + t0 + tt) * (3 * C_EMB)
                                          + 2 * C_EMB + h * DH + db];
#pragma unroll
        for (int j = 0; j < 8; ++j) tile[tt][db + j] = (unsigned short)v[j];
    }
    __syncthreads();
#pragma unroll
    for (int i = 0; i < 2; ++i) {
        int e = i * 256 + threadIdx.x;
        int d = e >> 3, tb = (e & 7) * 8;
        short8v ov;
#pragma unroll
        for (int j = 0; j < 8; ++j) ov[j] = (short)tile[tb + j][d];
        *(short8v*)&vt[(size_t)(bh * DH + d) * T_SEQ + t0 + tb] = ov;
    }
}

// ------------- flash attention: swapped QK^T, tri-buffer, 1 barrier/tile -------------
// S^T = mfma(K, Q): lane holds s[sub][r] = S[key = sub*16+lg*4+r][q = lr]
// O^T = mfma(V^T, P): lane holds o[n][r] = O[d = n*16+lg*4+r][q = lr]
template<bool MASK>
__device__ __forceinline__ void attn_tile(const unsigned short* __restrict__ Ksb,
                                          const unsigned short* __restrict__ Vsb,
                                          unsigned short* __restrict__ Psw,
                                          short8v qa0, short8v qa1,
                                          float4v (&o)[4], float& m_run, float& l_run,
                                          int lr, int lg, int wq) {
    const int swz = lr & 7;
    float4v s[4];
    __builtin_amdgcn_s_setprio(1);
#pragma unroll
    for (int sub = 0; sub < 4; ++sub) {
        const unsigned short* rowp = Ksb + (sub * 16 + lr) * 64;
        short8v kb0 = *(const short8v*)&rowp[(lg ^ swz) * 8];
        short8v kb1 = *(const short8v*)&rowp[((4 + lg) ^ swz) * 8];
        float4v acc = (float4v){0.f, 0.f, 0.f, 0.f};
        acc = __builtin_amdgcn_mfma_f32_16x16x32_bf16(kb0, qa0, acc, 0, 0, 0);
        acc = __builtin_amdgcn_mfma_f32_16x16x32_bf16(kb1, qa1, acc, 0, 0, 0);
        s[sub] = acc;
    }
    __builtin_amdgcn_s_setprio(0);
    if (MASK) {
#pragma unroll
        for (int sub = 0; sub < 4; ++sub)
#pragma unroll
            for (int r = 0; r < 4; ++r)
                s[sub][r] = (sub * 16 + lg * 4 + r <= wq + lr) ? s[sub][r] : -1e30f;
    }
    // partial (in-lane) row max; cross-lane reduce ONLY on the rare rescale path.
    // __any(partial > m+THR) == (full_rowmax > m+THR), since rowmax = max of partials.
    float pmax = s[0][0];
#pragma unroll
    for (int sub = 0; sub < 4; ++sub)
#pragma unroll
        for (int r = 0; r < 4; ++r) pmax = fmaxf(pmax, s[sub][r]);

    if (__any(pmax - m_run > DEFER_THR)) {
        float fm = fmaxf(pmax, __shfl_xor(pmax, 16));
        fm = fmaxf(fm, __shfl_xor(fm, 32));
        float nm = fmaxf(m_run, fm);
        float alpha = exp2f((m_run - nm) * CEXP);
        m_run = nm;
#pragma unroll
        for (int n = 0; n < 4; ++n) o[n] *= alpha;
        l_run *= alpha;
    }
    const float mc = m_run * CEXP;
    float p[4][4];
    float rowsum = 0.f;
#pragma unroll
    for (int sub = 0; sub < 4; ++sub)
#pragma unroll
        for (int r = 0; r < 4; ++r) {
            p[sub][r] = exp2f(__builtin_fmaf(s[sub][r], CEXP, -mc));
            rowsum += p[sub][r];
        }
    l_run += rowsum;   // per-lane partial; reduced once in epilogue

    // P bounce through wave-private [16][36] (row = q = lr, col = key within 32-chunk)
#pragma unroll
    for (int kk = 0; kk < 2; ++kk) {
#pragma unroll
        for (int si = 0; si < 2; ++si) {
            const int sub = kk * 2 + si;
            unsigned int u0 = cvtpk_bf16(p[sub][0], p[sub][1]);
            unsigned int u1 = cvtpk_bf16(p[sub][2], p[sub][3]);
            *(unsigned int*)&Psw[lr * 36 + si * 16 + lg * 4]     = u0;
            *(unsigned int*)&Psw[lr * 36 + si * 16 + lg * 4 + 2] = u1;
        }
        short8v pb = *(const short8v*)&Psw[lr * 36 + lg * 8];
        __builtin_amdgcn_s_setprio(1);
#pragma unroll
        for (int n = 0; n < 4; ++n) {
            short8v vb = *(const short8v*)&Vsb[(n * 16 + lr) * 64 + ((kk * 4 + lg) ^ swz) * 8];
            o[n] = __builtin_amdgcn_mfma_f32_16x16x32_bf16(vb, pb, o[n], 0, 0, 0);
        }
        __builtin_amdgcn_s_setprio(0);
    }
}

__global__ __launch_bounds__(256) void k_attn(const unsigned short* __restrict__ qkv,
                                              const unsigned short* __restrict__ vt,
                                              unsigned short* __restrict__ aout) {
    __shared__ __align__(16) unsigned short Ks[3][64 * 64];
    __shared__ __align__(16) unsigned short Vs[3][64 * 64];
    __shared__ __align__(16) unsigned short Ps[4][16 * 36];

    const int tid = threadIdx.x;
    const int lane = tid & 63;
    const int w = tid >> 6;
    const int lr = lane & 15;
    const int lg = lane >> 4;

    // XCD-chunked swizzle: 128 consecutive wg per XCD = 4 whole (b,h) heads -> K/V L2-resident
    const int lin = blockIdx.x;                  // grid = 1024
    const int wg = (lin & 7) * 128 + (lin >> 3);
    const int bh = wg >> 5;
    const int q0 = (31 - (wg & 31)) * 64;        // heavy q-blocks first within chunk
    const int b = bh >> 4, h = bh & 15;

    // Q fragment (16 q-rows per wave; q = lr)
    const unsigned short* qrowp =
        qkv + (size_t)(b * T_SEQ + q0 + w * 16 + lr) * (3 * C_EMB) + h * DH + lg * 8;
    short8v qa0 = *(const short8v*)qrowp;
    short8v qa1 = *(const short8v*)(qrowp + 32);

    float4v o[4];
    float m_run = -1e30f, l_run = 0.f;
#pragma unroll
    for (int n = 0; n < 4; ++n) o[n] = (float4v){0.f, 0.f, 0.f, 0.f};

    // staging sources (pre-swizzled: chunk ^= row so linear gload_lds lands swizzled)
    const int lc = ((tid & 7) ^ ((tid >> 3) & 7)) * 8;
    const unsigned short* kbase =
        qkv + (size_t)(b * T_SEQ + (tid >> 3)) * (3 * C_EMB) + C_EMB + h * DH + lc;
    const unsigned short* vbase = vt + (size_t)(bh * DH + (tid >> 3)) * T_SEQ + lc;

    unsigned short* Psw = &Ps[w][0];
    const int wq = w * 16;
    const int nt = q0 / 64 + 1;

#define A_STAGE(buf, t)                                                            \
    do {                                                                           \
        const size_t kv0_ = (size_t)(t) * 64;                                      \
        gload_lds16(kbase + kv0_ * 3 * C_EMB, &Ks[buf][tid * 8]);                  \
        gload_lds16(kbase + (kv0_ + 32) * 3 * C_EMB, &Ks[buf][2048 + tid * 8]);    \
        gload_lds16(vbase + kv0_, &Vs[buf][tid * 8]);                              \
        gload_lds16(vbase + (size_t)32 * T_SEQ + kv0_, &Vs[buf][2048 + tid * 8]);  \
    } while (0)

    A_STAGE(0, 0);
    if (nt > 1) A_STAGE(1, 1);

    int cur = 0;
    for (int t = 0; t < nt - 1; ++t) {
        asm volatile("s_waitcnt vmcnt(4)" ::: "memory");   // tile t staged; t+1 in flight
        block_barrier();
        if (t + 2 < nt) A_STAGE((cur == 0 ? 2 : cur - 1), t + 2);
        attn_tile<false>(&Ks[cur][0], &Vs[cur][0], Psw, qa0, qa1, o, m_run, l_run, lr, lg, wq);
        cur = (cur == 2) ? 0 : cur + 1;
    }
    // diagonal (masked) tile
    asm volatile("s_waitcnt vmcnt(0)" ::: "memory");
    block_barrier();
    attn_tile<true>(&Ks[cur][0], &Vs[cur][0], Psw, qa0, qa1, o, m_run, l_run, lr, lg, wq);
#undef A_STAGE

    // deferred l reduction (across the 4 lg replicas of each q)
    float lt = l_run;
    lt += __shfl_xor(lt, 16);
    lt += __shfl_xor(lt, 32);
    const float rl = 1.0f / lt;
    const int trow = b * T_SEQ + q0 + wq + lr;
#pragma unroll
    for (int n = 0; n < 4; ++n) {
        uint2v uu;
        uu.x = cvtpk_bf16(o[n][0] * rl, o[n][1] * rl);
        uu.y = cvtpk_bf16(o[n][2] * rl, o[n][3] * rl);
        *(uint2v*)&aout[(size_t)trow * C_EMB + h * DH + n * 16 + lg * 4] = uu;
    }
}

extern "C" void kernel_launch(void* const* d_in, const int* in_sizes, int n_in,
                              void* d_out, int out_size, void* d_ws, size_t ws_size,
                              hipStream_t stream) {
    const float* x = (const float*)d_in[0];
    const float* Wqkv = (const float*)d_in[1];
    const float* Wproj = (const float*)d_in[2];
    float* out = (float*)d_out;

    unsigned short* xb     = (unsigned short*)d_ws;
    unsigned short* wqkvT  = xb + (size_t)M_ROWS * C_EMB;
    unsigned short* wprojT = wqkvT + (size_t)3 * C_EMB * C_EMB;
    unsigned short* qkvb   = wprojT + (size_t)C_EMB * C_EMB;
    unsigned short* vtb    = qkvb + (size_t)M_ROWS * 3 * C_EMB;
    unsigned short* attb   = vtb + (size_t)M_ROWS * C_EMB;

    k_cvt_x<<<(M_ROWS * C_EMB / 4 + 255) / 256, 256, 0, stream>>>(x, xb, M_ROWS * C_EMB / 4);
    k_transpose_cvt<<<dim3(3 * C_EMB / 64, C_EMB / 64), 256, 0, stream>>>(Wqkv, wqkvT, C_EMB, 3 * C_EMB);
    k_transpose_cvt<<<dim3(C_EMB / 64, C_EMB / 64), 256, 0, stream>>>(Wproj, wprojT, C_EMB, C_EMB);
    k_gemm_bt<<<dim3(3 * C_EMB / 128, M_ROWS / 128), 256, 0, stream>>>(xb, wqkvT, (void*)qkvb,
                                                                       M_ROWS, 3 * C_EMB, C_EMB, 0);
    k_transpose_v<<<dim3(T_SEQ / 64, B_SZ * NH), 256, 0, stream>>>(qkvb, vtb);
    k_attn<<<dim3(B_SZ * NH * T_SEQ / 64), 256, 0, stream>>>(qkvb, vtb, attb);
    k_gemm_bt<<<dim3(C_EMB / 128, M_ROWS / 128), 256, 0, stream>>>(attb, wprojT, (void*)out,
                                                                   M_ROWS, C_EMB, C_EMB, 1);
}

// Round 6
// 117.011 us; speedup vs baseline: 1.2601x; 1.2601x over previous
//
#include <hip/hip_runtime.h>
#include <stdint.h>

typedef __attribute__((ext_vector_type(8))) short short8v;
typedef __attribute__((ext_vector_type(4))) float float4v;
typedef __attribute__((ext_vector_type(4))) unsigned short ushort4v;
typedef __attribute__((ext_vector_type(2))) unsigned int uint2v;
typedef __attribute__((ext_vector_type(4))) unsigned int uint4v;

#define B_SZ 2
#define T_SEQ 2048
#define C_EMB 1024
#define NH 16
#define DH 64
#define M_ROWS (B_SZ * T_SEQ)
#define CEXP 0.18033688f        /* (1/sqrt(64)) * log2(e) */
#define DEFER_THR 44.3614f      /* 8 / CEXP -> P bounded by 2^8 */

__device__ __forceinline__ unsigned short f2bf(float f) {
    unsigned int u = __float_as_uint(f);
    u += 0x7FFFu + ((u >> 16) & 1u);   // RTNE
    return (unsigned short)(u >> 16);
}

__device__ __forceinline__ unsigned int cvtpk_bf16(float lo, float hi) {
    unsigned int r;
    asm("v_cvt_pk_bf16_f32 %0, %1, %2" : "=v"(r) : "v"(lo), "v"(hi));
    return r;
}

__device__ __forceinline__ void gload_lds16(const void* g, void* s) {
    __builtin_amdgcn_global_load_lds(
        (const __attribute__((address_space(1))) void*)g,
        (__attribute__((address_space(3))) void*)s, 16, 0, 0);
}

__device__ __forceinline__ void memfence_sched() { asm volatile("" ::: "memory"); }

__device__ __forceinline__ void block_barrier() {
    memfence_sched();
    __builtin_amdgcn_s_barrier();
    memfence_sched();
}

// ---------------- x f32 -> bf16 ----------------
__global__ __launch_bounds__(256) void k_cvt_x(const float* __restrict__ in,
                                               unsigned short* __restrict__ out, int n4) {
    int i = blockIdx.x * 256 + threadIdx.x;
    if (i >= n4) return;
    float4v v = ((const float4v*)in)[i];
    ushort4v o;
    o.x = f2bf(v.x); o.y = f2bf(v.y); o.z = f2bf(v.z); o.w = f2bf(v.w);
    ((ushort4v*)out)[i] = o;
}

// ------------- W f32 [R][C] -> bf16 [C][R] -------------
__global__ __launch_bounds__(256) void k_transpose_cvt(const float* __restrict__ in,
                                                       unsigned short* __restrict__ out,
                                                       int R, int C) {
    __shared__ float tile[64][65];
    int c0 = blockIdx.x * 64;
    int r0 = blockIdx.y * 64;
#pragma unroll
    for (int i = 0; i < 16; ++i) {
        int e = i * 256 + threadIdx.x;
        int r = e >> 6, c = e & 63;
        tile[r][c] = in[(size_t)(r0 + r) * C + c0 + c];
    }
    __syncthreads();
#pragma unroll
    for (int i = 0; i < 16; ++i) {
        int e = i * 256 + threadIdx.x;
        int r = e >> 6, c = e & 63;
        out[(size_t)(c0 + r) * R + r0 + c] = f2bf(tile[c][r]);
    }
}

// ------------- GEMM: C = A * Bt^T, tri-buffered single-barrier pipeline -------------
__global__ __launch_bounds__(256) void k_gemm_bt(const unsigned short* __restrict__ A,
                                                 const unsigned short* __restrict__ Bt,
                                                 void* __restrict__ Cout,
                                                 int M, int N, int K, int out_f32) {
    __shared__ __align__(16) unsigned short As[3][128 * 32];
    __shared__ __align__(16) unsigned short Bs[3][128 * 32];

    const int tid = threadIdx.x;
    const int lane = tid & 63;
    const int w = tid >> 6;
    const int lr = lane & 15;
    const int lg = lane >> 4;
    const int wr = (w >> 1) * 64;
    const int wc = (w & 1) * 64;

    // XCD-chunked bijective swizzle (nwg % 8 == 0 guaranteed by launch shapes)
    const int gx = gridDim.x;
    const int nwg = gx * gridDim.y;
    const int lin = blockIdx.y * gx + blockIdx.x;
    const int q8 = nwg >> 3;
    const int wg = (lin & 7) * q8 + (lin >> 3);
    const int mb = wg / gx;
    const int nb = wg - mb * gx;
    const int m0 = mb * 128;
    const int n0 = nb * 128;

    const unsigned short* aptr = A + (size_t)(m0 + (tid >> 2)) * K + (tid & 3) * 8;
    const unsigned short* bptr = Bt + (size_t)(n0 + (tid >> 2)) * K + (tid & 3) * 8;

    float4v acc[4][4];
#pragma unroll
    for (int i = 0; i < 4; ++i)
#pragma unroll
        for (int j = 0; j < 4; ++j) acc[i][j] = (float4v){0.f, 0.f, 0.f, 0.f};

#define G_STAGE(buf, t)                                                        \
    do {                                                                       \
        const int k0_ = (t) * 32;                                              \
        gload_lds16(aptr + k0_, &As[buf][tid * 8]);                            \
        gload_lds16(aptr + (size_t)64 * K + k0_, &As[buf][2048 + tid * 8]);    \
        gload_lds16(bptr + k0_, &Bs[buf][tid * 8]);                            \
        gload_lds16(bptr + (size_t)64 * K + k0_, &Bs[buf][2048 + tid * 8]);    \
    } while (0)

    const int NT = K >> 5;
    G_STAGE(0, 0);
    G_STAGE(1, 1);

    int cur = 0;
    for (int t = 0; t < NT; ++t) {
        if (t < NT - 1) { asm volatile("s_waitcnt vmcnt(4)" ::: "memory"); }
        else           { asm volatile("s_waitcnt vmcnt(0)" ::: "memory"); }
        block_barrier();
        if (t + 2 < NT) { G_STAGE((cur == 0 ? 2 : cur - 1), t + 2); }

        short8v af[4], bf[4];
#pragma unroll
        for (int i = 0; i < 4; ++i)
            af[i] = *(const short8v*)&As[cur][(wr + i * 16 + lr) * 32 + lg * 8];
#pragma unroll
        for (int i = 0; i < 4; ++i)
            bf[i] = *(const short8v*)&Bs[cur][(wc + i * 16 + lr) * 32 + lg * 8];
        __builtin_amdgcn_s_setprio(1);
#pragma unroll
        for (int mi = 0; mi < 4; ++mi)
#pragma unroll
            for (int ni = 0; ni < 4; ++ni)
                acc[mi][ni] = __builtin_amdgcn_mfma_f32_16x16x32_bf16(af[mi], bf[ni],
                                                                      acc[mi][ni], 0, 0, 0);
        __builtin_amdgcn_s_setprio(0);
        cur = (cur == 2) ? 0 : cur + 1;
    }
#undef G_STAGE

#pragma unroll
    for (int mi = 0; mi < 4; ++mi) {
#pragma unroll
        for (int ni = 0; ni < 4; ++ni) {
            int row = m0 + wr + mi * 16 + lg * 4;
            int col = n0 + wc + ni * 16 + lr;
            if (out_f32) {
                float* Cf = (float*)Cout;
#pragma unroll
                for (int r = 0; r < 4; ++r) Cf[(size_t)(row + r) * N + col] = acc[mi][ni][r];
            } else {
                unsigned short* Cb = (unsigned short*)Cout;
#pragma unroll
                for (int r = 0; r < 4; ++r) Cb[(size_t)(row + r) * N + col] = f2bf(acc[mi][ni][r]);
            }
        }
    }
}

// ------------- V-part of qkv -> v_t[b,h,d,t'] (bf16), key-permuted within 32-chunks -------------
// slot(c) = 8*((c>>2)&3) + 4*(c>>4) + (c&3)  for c = key & 31, so the PV B-fragment
// (key-slots 8*lg+j per lane) coincides with the lanes' in-register S^T fragments.
__global__ __launch_bounds__(256) void k_transpose_v(const unsigned short* __restrict__ qkv,
                                                     unsigned short* __restrict__ vt) {
    __shared__ unsigned short tile[64][72];
    int t0 = blockIdx.x * 64;
    int bh = blockIdx.y;
    int b = bh >> 4, h = bh & 15;
#pragma unroll
    for (int i = 0; i < 2; ++i) {
        int e = i * 256 + threadIdx.x;
        int tt = e >> 3, db = (e & 7) * 8;
        short8v v = *(const short8v*)&qkv[(size_t)(b * T_SEQ + t0 + tt) * (3 * C_EMB)
                                          + 2 * C_EMB + h * DH + db];
#pragma unroll
        for (int j = 0; j < 8; ++j) tile[tt][db + j] = (unsigned short)v[j];
    }
    __syncthreads();
#pragma unroll
    for (int i = 0; i < 2; ++i) {
        int e = i * 256 + threadIdx.x;
        int d = e >> 3, tb = (e & 7) * 8;
        short8v ov;
        // slots tb..tb+7 hold keys chunkbase + 16*(j>>2) + 4*lgp + (j&3), lgp = (tb>>3)&3
#pragma unroll
        for (int j = 0; j < 8; ++j)
            ov[j] = (short)tile[(tb & 32) + ((tb >> 3) & 3) * 4 + 16 * (j >> 2) + (j & 3)][d];
        *(short8v*)&vt[(size_t)(bh * DH + d) * T_SEQ + t0 + tb] = ov;
    }
}

// ------------- flash attention: swapped QK^T, dbuf, zero-LDS P -------------
// S^T = mfma(K, Q): lane holds s[sub][r] = S[key = sub*16+lg*4+r][q = lr]
// O^T = mfma(V'^T, P'): V' key-permuted so lane's own p regs are its B-fragment
template<bool MASK>
__device__ __forceinline__ void attn_tile(const unsigned short* __restrict__ Ksb,
                                          const unsigned short* __restrict__ Vsb,
                                          short8v qa0, short8v qa1,
                                          float4v (&o)[4], float& m_run, float& l_run,
                                          int lr, int lg, int wq) {
    const int swz = lr & 7;
    float4v s[4];
    __builtin_amdgcn_s_setprio(1);
#pragma unroll
    for (int sub = 0; sub < 4; ++sub) {
        const unsigned short* rowp = Ksb + (sub * 16 + lr) * 64;
        short8v kb0 = *(const short8v*)&rowp[(lg ^ swz) * 8];
        short8v kb1 = *(const short8v*)&rowp[((4 + lg) ^ swz) * 8];
        float4v acc = (float4v){0.f, 0.f, 0.f, 0.f};
        acc = __builtin_amdgcn_mfma_f32_16x16x32_bf16(kb0, qa0, acc, 0, 0, 0);
        acc = __builtin_amdgcn_mfma_f32_16x16x32_bf16(kb1, qa1, acc, 0, 0, 0);
        s[sub] = acc;
    }
    __builtin_amdgcn_s_setprio(0);
    if (MASK) {
#pragma unroll
        for (int sub = 0; sub < 4; ++sub)
#pragma unroll
            for (int r = 0; r < 4; ++r)
                s[sub][r] = (sub * 16 + lg * 4 + r <= wq + lr) ? s[sub][r] : -1e30f;
    }
    // partial (in-lane) row max; cross-lane reduce ONLY on the rare rescale path.
    float pmax = s[0][0];
#pragma unroll
    for (int sub = 0; sub < 4; ++sub)
#pragma unroll
        for (int r = 0; r < 4; ++r) pmax = fmaxf(pmax, s[sub][r]);

    if (__any(pmax - m_run > DEFER_THR)) {
        float fm = fmaxf(pmax, __shfl_xor(pmax, 16));
        fm = fmaxf(fm, __shfl_xor(fm, 32));
        float nm = fmaxf(m_run, fm);
        float alpha = exp2f((m_run - nm) * CEXP);
        m_run = nm;
#pragma unroll
        for (int n = 0; n < 4; ++n) o[n] *= alpha;
        l_run *= alpha;
    }
    const float mc = m_run * CEXP;
    float p[4][4];
    float rowsum = 0.f;
#pragma unroll
    for (int sub = 0; sub < 4; ++sub)
#pragma unroll
        for (int r = 0; r < 4; ++r) {
            p[sub][r] = exp2f(__builtin_fmaf(s[sub][r], CEXP, -mc));
            rowsum += p[sub][r];
        }
    l_run += rowsum;   // per-lane partial; reduced once in epilogue

    // P stays in registers: lane's slots 8*lg..8*lg+7 = p[2kk][0..3] ++ p[2kk+1][0..3]
#pragma unroll
    for (int kk = 0; kk < 2; ++kk) {
        uint4v up;
        up.x = cvtpk_bf16(p[2 * kk][0],     p[2 * kk][1]);
        up.y = cvtpk_bf16(p[2 * kk][2],     p[2 * kk][3]);
        up.z = cvtpk_bf16(p[2 * kk + 1][0], p[2 * kk + 1][1]);
        up.w = cvtpk_bf16(p[2 * kk + 1][2], p[2 * kk + 1][3]);
        short8v pb = *(short8v*)&up;
        __builtin_amdgcn_s_setprio(1);
#pragma unroll
        for (int n = 0; n < 4; ++n) {
            short8v vb = *(const short8v*)&Vsb[(n * 16 + lr) * 64 + ((kk * 4 + lg) ^ swz) * 8];
            o[n] = __builtin_amdgcn_mfma_f32_16x16x32_bf16(vb, pb, o[n], 0, 0, 0);
        }
        __builtin_amdgcn_s_setprio(0);
    }
}

__global__ __launch_bounds__(256, 4) void k_attn(const unsigned short* __restrict__ qkv,
                                                 const unsigned short* __restrict__ vt,
                                                 unsigned short* __restrict__ aout) {
    __shared__ __align__(16) unsigned short Ks[2][64 * 64];
    __shared__ __align__(16) unsigned short Vs[2][64 * 64];

    const int tid = threadIdx.x;
    const int lane = tid & 63;
    const int w = tid >> 6;
    const int lr = lane & 15;
    const int lg = lane >> 4;

    const int bh = blockIdx.x;
    const int q0 = ((int)gridDim.y - 1 - (int)blockIdx.y) * 64;  // heavy blocks first
    const int b = bh >> 4, h = bh & 15;

    // Q fragment (16 q-rows per wave; q = lr)
    const unsigned short* qrowp =
        qkv + (size_t)(b * T_SEQ + q0 + w * 16 + lr) * (3 * C_EMB) + h * DH + lg * 8;
    short8v qa0 = *(const short8v*)qrowp;
    short8v qa1 = *(const short8v*)(qrowp + 32);

    float4v o[4];
    float m_run = -1e30f, l_run = 0.f;
#pragma unroll
    for (int n = 0; n < 4; ++n) o[n] = (float4v){0.f, 0.f, 0.f, 0.f};

    // staging sources (pre-swizzled: chunk ^= row so linear gload_lds lands swizzled)
    const int lc = ((tid & 7) ^ ((tid >> 3) & 7)) * 8;
    const unsigned short* kbase =
        qkv + (size_t)(b * T_SEQ + (tid >> 3)) * (3 * C_EMB) + C_EMB + h * DH + lc;
    const unsigned short* vbase = vt + (size_t)(bh * DH + (tid >> 3)) * T_SEQ + lc;

    const int wq = w * 16;
    const int nt = q0 / 64 + 1;

    // prologue stage tile 0 -> buf 0
    gload_lds16(kbase, &Ks[0][tid * 8]);
    gload_lds16(kbase + (size_t)32 * 3 * C_EMB, &Ks[0][2048 + tid * 8]);
    gload_lds16(vbase, &Vs[0][tid * 8]);
    gload_lds16(vbase + (size_t)32 * T_SEQ, &Vs[0][2048 + tid * 8]);

    int cur = 0;
    for (int t = 0; t < nt - 1; ++t) {
        const size_t kv0 = (size_t)(t + 1) * 64;
        // prefetch next tile into other buffer
        gload_lds16(kbase + kv0 * 3 * C_EMB, &Ks[cur ^ 1][tid * 8]);
        gload_lds16(kbase + (kv0 + 32) * 3 * C_EMB, &Ks[cur ^ 1][2048 + tid * 8]);
        gload_lds16(vbase + kv0, &Vs[cur ^ 1][tid * 8]);
        gload_lds16(vbase + (size_t)32 * T_SEQ + kv0, &Vs[cur ^ 1][2048 + tid * 8]);
        asm volatile("s_waitcnt vmcnt(4)" ::: "memory");   // current tile staged; next in flight
        block_barrier();
        attn_tile<false>(&Ks[cur][0], &Vs[cur][0], qa0, qa1, o, m_run, l_run, lr, lg, wq);
        block_barrier();
        cur ^= 1;
    }
    // diagonal (masked) tile
    asm volatile("s_waitcnt vmcnt(0)" ::: "memory");
    block_barrier();
    attn_tile<true>(&Ks[cur][0], &Vs[cur][0], qa0, qa1, o, m_run, l_run, lr, lg, wq);

    // deferred l reduction (across the 4 lg replicas of each q)
    float lt = l_run;
    lt += __shfl_xor(lt, 16);
    lt += __shfl_xor(lt, 32);
    const float rl = 1.0f / lt;
    const int trow = b * T_SEQ + q0 + wq + lr;
#pragma unroll
    for (int n = 0; n < 4; ++n) {
        uint2v uu;
        uu.x = cvtpk_bf16(o[n][0] * rl, o[n][1] * rl);
        uu.y = cvtpk_bf16(o[n][2] * rl, o[n][3] * rl);
        *(uint2v*)&aout[(size_t)trow * C_EMB + h * DH + n * 16 + lg * 4] = uu;
    }
}

extern "C" void kernel_launch(void* const* d_in, const int* in_sizes, int n_in,
                              void* d_out, int out_size, void* d_ws, size_t ws_size,
                              hipStream_t stream) {
    const float* x = (const float*)d_in[0];
    const float* Wqkv = (const float*)d_in[1];
    const float* Wproj = (const float*)d_in[2];
    float* out = (float*)d_out;

    unsigned short* xb     = (unsigned short*)d_ws;
    unsigned short* wqkvT  = xb + (size_t)M_ROWS * C_EMB;
    unsigned short* wprojT = wqkvT + (size_t)3 * C_EMB * C_EMB;
    unsigned short* qkvb   = wprojT + (size_t)C_EMB * C_EMB;
    unsigned short* vtb    = qkvb + (size_t)M_ROWS * 3 * C_EMB;
    unsigned short* attb   = vtb + (size_t)M_ROWS * C_EMB;

    k_cvt_x<<<(M_ROWS * C_EMB / 4 + 255) / 256, 256, 0, stream>>>(x, xb, M_ROWS * C_EMB / 4);
    k_transpose_cvt<<<dim3(3 * C_EMB / 64, C_EMB / 64), 256, 0, stream>>>(Wqkv, wqkvT, C_EMB, 3 * C_EMB);
    k_transpose_cvt<<<dim3(C_EMB / 64, C_EMB / 64), 256, 0, stream>>>(Wproj, wprojT, C_EMB, C_EMB);
    k_gemm_bt<<<dim3(3 * C_EMB / 128, M_ROWS / 128), 256, 0, stream>>>(xb, wqkvT, (void*)qkvb,
                                                                       M_ROWS, 3 * C_EMB, C_EMB, 0);
    k_transpose_v<<<dim3(T_SEQ / 64, B_SZ * NH), 256, 0, stream>>>(qkvb, vtb);
    k_attn<<<dim3(B_SZ * NH, T_SEQ / 64), 256, 0, stream>>>(qkvb, vtb, attb);
    k_gemm_bt<<<dim3(C_EMB / 128, M_ROWS / 128), 256, 0, stream>>>(attb, wprojT, (void*)out,
                                                                   M_ROWS, C_EMB, C_EMB, 1);
}